// Round 18
// baseline (744.303 us; speedup 1.0000x reference)
//
#include <hip/hip_runtime.h>

#define F 128
static const int N0 = 100000, N1 = 25000, N2 = 6250;

typedef unsigned short u16;
typedef unsigned int   u32;
typedef __attribute__((ext_vector_type(8))) short bf16x8;
typedef __attribute__((ext_vector_type(4))) float f32x4;

__device__ __forceinline__ float bf2f(u16 u) {
    union { u32 i; float f; } v; v.i = ((u32)u) << 16; return v.f;
}
__device__ __forceinline__ u16 f2bf(float f) {
    u32 u = __float_as_uint(f);
    u += 0x7fff + ((u >> 16) & 1);   // RNE
    return (u16)(u >> 16);
}

// ---- segment tables ----
struct Seg7 {
    const int* src[7];
    const int* dst[7];
    int end[7];      // cumulative edge-count boundaries
    int cbase[7];    // row-segment base in concatenated cnt/rowptr
};
struct SegO {        // the 3 GCN graphs (out-degree histograms)
    const int* src[3];
    int end[3];
    int obase[3];
};
struct W7 { const float* w[7]; };

#define EPT 4            // fill: edges per thread per chunk
#define CEPT 8           // count/od: edges per thread (independent atomic chains)
#define AST (F + 8)      // LDS A-tile stride (u16)
#define SM32  (64*(32+8)*2 + 128*(32+8)*2 + 128*4)

// ================= device bodies =================

// small-K dense MFMA matmul (K=32, fp32 A: the embedding) — W staged in LDS
__device__ __forceinline__ void dev_mm32(char* smem, const float* __restrict__ Ap,
                                         const float* __restrict__ W,
                                         const float* __restrict__ bias,
                                         u16* __restrict__ out, int M, int blk) {
    const int K = 32;
    const int KST = K + 8;
    u16* Al = (u16*)smem;
    u16* Wt = (u16*)(smem + 64 * KST * 2);
    float* bl = (float*)(smem + 64 * KST * 2 + 128 * KST * 2);
    int tid = threadIdx.x;
    int m0 = blk * 64;

    for (int i = tid; i < K * 128; i += 256) {
        int k = i >> 7, n = i & 127;
        Wt[n * KST + k] = f2bf(W[i]);
    }
    for (int i = tid; i < 64 * K; i += 256) {
        int r = i / K, c = i % K;
        int gr = m0 + r;
        Al[r * KST + c] = (gr < M) ? f2bf(Ap[(size_t)gr * K + c]) : (u16)0;
    }
    if (tid < 128) bl[tid] = bias[tid];
    __syncthreads();

    int w = tid >> 6, lane = tid & 63, m16 = lane & 15, quad = lane >> 4;
    f32x4 acc[8];
#pragma unroll
    for (int t = 0; t < 8; t++)
#pragma unroll
        for (int r = 0; r < 4; r++) acc[t][r] = 0.f;

    {
        bf16x8 af = *(const bf16x8*)&Al[(w * 16 + m16) * KST + quad * 8];
#pragma unroll
        for (int t = 0; t < 8; t++) {
            bf16x8 bf = *(const bf16x8*)&Wt[(t * 16 + m16) * KST + quad * 8];
            acc[t] = __builtin_amdgcn_mfma_f32_16x16x32_bf16(af, bf, acc[t], 0, 0, 0);
        }
    }
#pragma unroll
    for (int t = 0; t < 8; t++) {
#pragma unroll
        for (int r = 0; r < 4; r++) {
            int gr = m0 + w * 16 + quad * 4 + r;
            if (gr >= M) continue;
            int gc = t * 16 + m16;
            out[(size_t)gr * F + gc] = f2bf(acc[t][r] + bl[gc]);
        }
    }
}

// LDS-free K=128 matmul: A-fragments straight from global (row clamped; rows
// past M never written), B-fragments from global bf16 W^T (L1-resident).
template <bool MASK>
__device__ __forceinline__ void dev_mmd(const u16* __restrict__ Ap,
                                        const u16* __restrict__ Wtg,
                                        const float* __restrict__ bias,
                                        u16* __restrict__ out,
                                        const int* __restrict__ rowptr,
                                        int M, int blk) {
    int tid = threadIdx.x;
    int wv = tid >> 6, lane = tid & 63, m16 = lane & 15, quad = lane >> 4;
    int m0 = blk * 64;
    int arow = m0 + wv * 16 + m16;
    if (arow >= M) arow = M - 1;
    const u16* Arow = Ap + (size_t)arow * F;

    f32x4 acc[8];
#pragma unroll
    for (int t = 0; t < 8; t++)
#pragma unroll
        for (int r = 0; r < 4; r++) acc[t][r] = 0.f;

#pragma unroll
    for (int k0 = 0; k0 < F; k0 += 32) {
        bf16x8 af = *(const bf16x8*)&Arow[k0 + quad * 8];
#pragma unroll
        for (int t = 0; t < 8; t++) {
            bf16x8 bf = *(const bf16x8*)&Wtg[(t * 16 + m16) * F + k0 + quad * 8];
            acc[t] = __builtin_amdgcn_mfma_f32_16x16x32_bf16(af, bf, acc[t], 0, 0, 0);
        }
    }
#pragma unroll
    for (int t = 0; t < 8; t++) {
#pragma unroll
        for (int r = 0; r < 4; r++) {
            int gr = m0 + wv * 16 + quad * 4 + r;
            if (gr >= M) continue;
            int gc = t * 16 + m16;
            bool zrow = false;
            if (MASK) zrow = (rowptr[gr + 1] == rowptr[gr]);
            float v = acc[t][r] + bias[gc];
            out[(size_t)gr * F + gc] = zrow ? (u16)0 : f2bf(v);
        }
    }
}

// 32-lane-group CSR gather: 2 rows/wave, ushort4/lane, 8-wide unroll.
// MODE 0: mean; MODE 1: gcn (rsqrt0(od[col]) inline)
template <int MODE>
__device__ __forceinline__ void dev_gather32(const u16* __restrict__ feat,
                                             const int* __restrict__ rowptr,
                                             const int* __restrict__ col,
                                             const int* __restrict__ od,
                                             u16* __restrict__ out, int M, int blk) {
    int row = (blk * 256 + (int)threadIdx.x) >> 5;
    if (row >= M) return;
    int l32 = threadIdx.x & 31;
    int fo = l32 << 2;
    int beg = rowptr[row], end = rowptr[row + 1];
    float a0 = 0.f, a1 = 0.f, a2 = 0.f, a3 = 0.f;
    int j = beg;
    for (; j + 8 <= end; j += 8) {
        int cc[8];
#pragma unroll
        for (int t = 0; t < 8; t++) cc[t] = col[j + t];
        float ss[8];
#pragma unroll
        for (int t = 0; t < 8; t++) {
            if (MODE == 1) { int o = od[cc[t]]; ss[t] = o > 0 ? rsqrtf((float)o) : 0.f; }
            else ss[t] = 1.f;
        }
        ushort4 uu[8];
#pragma unroll
        for (int t = 0; t < 8; t++) uu[t] = *(const ushort4*)&feat[(size_t)cc[t] * F + fo];
#pragma unroll
        for (int t = 0; t < 8; t++) {
            a0 += bf2f(uu[t].x) * ss[t]; a1 += bf2f(uu[t].y) * ss[t];
            a2 += bf2f(uu[t].z) * ss[t]; a3 += bf2f(uu[t].w) * ss[t];
        }
    }
    for (; j < end; j++) {
        int c = col[j];
        float s = 1.f;
        if (MODE == 1) { int o = od[c]; s = o > 0 ? rsqrtf((float)o) : 0.f; }
        ushort4 u = *(const ushort4*)&feat[(size_t)c * F + fo];
        a0 += bf2f(u.x) * s; a1 += bf2f(u.y) * s;
        a2 += bf2f(u.z) * s; a3 += bf2f(u.w) * s;
    }
    int deg = end - beg;
    float fs = (MODE == 0) ? (deg > 0 ? 1.f / (float)deg : 0.f)
                           : (deg > 0 ? rsqrtf((float)deg) : 0.f);
    ushort4 o;
    o.x = f2bf(a0 * fs); o.y = f2bf(a1 * fs);
    o.z = f2bf(a2 * fs); o.w = f2bf(a3 * fs);
    *(ushort4*)&out[(size_t)row * F + fo] = o;
}

// head body, 32-lane groups: softmax(concat(g,d)@Wh+bh) -> fp32.
// GD: d-row gathered on the fly (mean over CSR, ushort4 lanes).
template <bool GD>
__device__ __forceinline__ void dev_head(char* smem, const u16* __restrict__ g,
                                         const u16* __restrict__ d,
                                         const int* __restrict__ rowptr,
                                         const int* __restrict__ col,
                                         const float* __restrict__ Wh,
                                         const float* __restrict__ bh,
                                         float* __restrict__ out, int M, int blk) {
    float* Wl = (float*)smem;          // 1280
    float* bl = (float*)(smem + 1280 * 4);
    int tid = threadIdx.x;
    for (int i = tid; i < 1280; i += 256) Wl[i] = Wh[i];
    if (tid < 5) bl[tid] = bh[tid];
    __syncthreads();

    int grp = tid >> 5;
    int l32 = tid & 31;
    int k0 = l32 << 2;
    for (int i = 0; i < 4; i++) {
        int row = blk * 32 + grp * 4 + i;
        if (row < M) {
            float dv[4];
            if (GD) {
                int beg = rowptr[row], end = rowptr[row + 1];
                dv[0] = dv[1] = dv[2] = dv[3] = 0.f;
                int j = beg;
                for (; j + 4 <= end; j += 4) {
                    int c0 = col[j], c1 = col[j + 1], c2 = col[j + 2], c3 = col[j + 3];
                    ushort4 u0 = *(const ushort4*)&d[(size_t)c0 * F + k0];
                    ushort4 u1 = *(const ushort4*)&d[(size_t)c1 * F + k0];
                    ushort4 u2 = *(const ushort4*)&d[(size_t)c2 * F + k0];
                    ushort4 u3 = *(const ushort4*)&d[(size_t)c3 * F + k0];
                    dv[0] += bf2f(u0.x) + bf2f(u1.x) + bf2f(u2.x) + bf2f(u3.x);
                    dv[1] += bf2f(u0.y) + bf2f(u1.y) + bf2f(u2.y) + bf2f(u3.y);
                    dv[2] += bf2f(u0.z) + bf2f(u1.z) + bf2f(u2.z) + bf2f(u3.z);
                    dv[3] += bf2f(u0.w) + bf2f(u1.w) + bf2f(u2.w) + bf2f(u3.w);
                }
                for (; j < end; j++) {
                    int c = col[j];
                    ushort4 u = *(const ushort4*)&d[(size_t)c * F + k0];
                    dv[0] += bf2f(u.x); dv[1] += bf2f(u.y);
                    dv[2] += bf2f(u.z); dv[3] += bf2f(u.w);
                }
                int deg = end - beg;
                float fs = deg > 0 ? 1.f / (float)deg : 0.f;
#pragma unroll
                for (int q = 0; q < 4; q++) dv[q] *= fs;
            } else {
                ushort4 du = *(const ushort4*)&d[(size_t)row * F + k0];
                dv[0] = bf2f(du.x); dv[1] = bf2f(du.y);
                dv[2] = bf2f(du.z); dv[3] = bf2f(du.w);
            }
            ushort4 gu = *(const ushort4*)&g[(size_t)row * F + k0];
            float gv[4] = {bf2f(gu.x), bf2f(gu.y), bf2f(gu.z), bf2f(gu.w)};
            float p[5];
#pragma unroll
            for (int o = 0; o < 5; o++) {
                float v = 0.f;
#pragma unroll
                for (int q = 0; q < 4; q++)
                    v += gv[q] * Wl[(k0 + q) * 5 + o] + dv[q] * Wl[(k0 + q + 128) * 5 + o];
                p[o] = v;
            }
#pragma unroll
            for (int o = 0; o < 5; o++) {
                float v = p[o];
                v += __shfl_xor(v, 16, 64);
                v += __shfl_xor(v, 8, 64);
                v += __shfl_xor(v, 4, 64);
                v += __shfl_xor(v, 2, 64);
                v += __shfl_xor(v, 1, 64);
                p[o] = v + bl[o];
            }
            if (l32 == 0) {
                float m = p[0];
#pragma unroll
                for (int o = 1; o < 5; o++) m = fmaxf(m, p[o]);
                float e[5], s = 0.f;
#pragma unroll
                for (int o = 0; o < 5; o++) { e[o] = expf(p[o] - m); s += e[o]; }
                float inv = 1.f / s;
#pragma unroll
                for (int o = 0; o < 5; o++) out[(size_t)row * 5 + o] = e[o] * inv;
            }
        }
    }
}

// ================= kernels =================

// L1: four roles — emb mm | W^T prep | dst histogram (return-atomics -> occ)
// | od histogram (fire-and-forget). ALL 4.8M atomics in one launch so they
// pipeline on the fabric together (split launches serialize the atomic floor).
__global__ __launch_bounds__(256) void k_count_emb(Seg7 S, SegO SO, W7 Wsrc,
                                                   u16* __restrict__ WtAll,
                                                   int* __restrict__ cnt,
                                                   int* __restrict__ od,
                                                   u16* __restrict__ occ,
                                                   int ETOT, int ETOTG,
                                                   const float* __restrict__ X,
                                                   const float* __restrict__ Wemb,
                                                   const float* __restrict__ bemb,
                                                   u16* __restrict__ h0,
                                                   int nbMM, int nbPrep, int nbCnt) {
    __shared__ char smem[SM32];
    int blk = blockIdx.x;
    if (blk < nbMM) {
        dev_mm32(smem, X, Wemb, bemb, h0, N0, blk);
        return;
    }
    if (blk < nbMM + nbPrep) {
        int g = (blk - nbMM) * 256 + threadIdx.x;   // < 7*16384
        int m = g >> 14, idx = g & 16383;
        int n = idx >> 7, k = idx & 127;
        WtAll[g] = f2bf(Wsrc.w[m][k * 128 + n]);    // coalesced writes
        return;
    }
    if (blk < nbMM + nbPrep + nbCnt) {
        int base = (blk - nbMM - nbPrep) * (256 * CEPT) + threadIdx.x;
        int ee[CEPT], grow[CEPT];
#pragma unroll
        for (int t = 0; t < CEPT; t++) {
            int e = base + t * 256;
            ee[t] = e;
            grow[t] = -1;
            if (e < ETOT) {
                int s = 0;
                while (e >= S.end[s]) s++;
                int le = e - ((s == 0) ? 0 : S.end[s - 1]);
                grow[t] = S.cbase[s] + S.dst[s][le];
            }
        }
        u32 r[CEPT];
#pragma unroll
        for (int t = 0; t < CEPT; t++)
            if (grow[t] >= 0) r[t] = atomicAdd((u32*)&cnt[grow[t]], 1u);
#pragma unroll
        for (int t = 0; t < CEPT; t++)
            if (grow[t] >= 0) occ[ee[t]] = (u16)r[t];
        return;
    }
    // od role: GCN src out-degree, fire-and-forget
    int base = (blk - nbMM - nbPrep - nbCnt) * (256 * CEPT) + threadIdx.x;
    int gs[CEPT];
#pragma unroll
    for (int t = 0; t < CEPT; t++) {
        int e = base + t * 256;
        gs[t] = -1;
        if (e < ETOTG) {
            int s = 0;
            while (e >= SO.end[s]) s++;
            int le = e - ((s == 0) ? 0 : SO.end[s - 1]);
            gs[t] = SO.obase[s] + SO.src[s][le];
        }
    }
#pragma unroll
    for (int t = 0; t < CEPT; t++)
        if (gs[t] >= 0) atomicAdd(&od[gs[t]], 1);
}

// L5: pure atomic-free XCD-windowed CSR fill (pos = rowptr[row] + occ[e])
__global__ __launch_bounds__(256) void k_fill(Seg7 S,
                                              const int* __restrict__ rowptr,
                                              const u16* __restrict__ occ,
                                              int* __restrict__ col, int ETOT,
                                              float invRow) {
    int win = blockIdx.x & 7;
    int base = ((int)blockIdx.x >> 3) * (256 * EPT) + threadIdx.x;
#pragma unroll
    for (int t = 0; t < EPT; t++) {
        int e = base + t * 256;
        if (e >= ETOT) break;
        int s = 0;
        while (e >= S.end[s]) s++;
        int le = e - ((s == 0) ? 0 : S.end[s - 1]);
        int grow = S.cbase[s] + S.dst[s][le];
        int w1 = (int)((float)grow * invRow); w1 = w1 > 7 ? 7 : w1;
        if (w1 == win) col[rowptr[grow] + (int)occ[e]] = S.src[s][le];
    }
}

// ---- multi-block exclusive scan over concatenated counts (3 phases) ----
#define SCHUNK 4096  // 1024 threads x 4
__global__ __launch_bounds__(1024) void k_scan1(const int* __restrict__ cnt,
                                                int* __restrict__ partial, int n) {
    __shared__ int red[1024];
    int tid = threadIdx.x;
    int base = blockIdx.x * SCHUNK + tid * 4;
    int s = 0;
#pragma unroll
    for (int j = 0; j < 4; j++) { int i = base + j; if (i < n) s += cnt[i]; }
    red[tid] = s;
    __syncthreads();
    for (int d = 512; d > 0; d >>= 1) {
        if (tid < d) red[tid] += red[tid + d];
        __syncthreads();
    }
    if (tid == 0) partial[blockIdx.x] = red[0];
}

__global__ __launch_bounds__(128) void k_scan2(int* __restrict__ partial, int G) {
    __shared__ int sh[128];
    int tid = threadIdx.x;
    sh[tid] = (tid < G) ? partial[tid] : 0;
    __syncthreads();
    for (int d = 1; d < 128; d <<= 1) {
        int t = (tid >= d) ? sh[tid - d] : 0;
        __syncthreads();
        sh[tid] += t;
        __syncthreads();
    }
    if (tid < G) partial[tid] = (tid > 0) ? sh[tid - 1] : 0;  // exclusive
    if (tid == 127) partial[G] = sh[127];                     // grand total
}

__global__ __launch_bounds__(1024) void k_scan3(const int* __restrict__ cnt,
                                                const int* __restrict__ partial,
                                                int* __restrict__ rowptr,
                                                int n, int G) {
    __shared__ int red[1024];
    int tid = threadIdx.x;
    int base = blockIdx.x * SCHUNK + tid * 4;
    int v0 = 0, v1 = 0, v2 = 0, v3 = 0;
    if (base + 0 < n) v0 = cnt[base + 0];
    if (base + 1 < n) v1 = cnt[base + 1];
    if (base + 2 < n) v2 = cnt[base + 2];
    if (base + 3 < n) v3 = cnt[base + 3];
    red[tid] = v0 + v1 + v2 + v3;
    __syncthreads();
    for (int d = 1; d < 1024; d <<= 1) {
        int t = (tid >= d) ? red[tid - d] : 0;
        __syncthreads();
        red[tid] += t;
        __syncthreads();
    }
    int off = partial[blockIdx.x] + ((tid > 0) ? red[tid - 1] : 0);
    if (base + 0 < n) { rowptr[base + 0] = off; off += v0; }
    if (base + 1 < n) { rowptr[base + 1] = off; off += v1; }
    if (base + 2 < n) { rowptr[base + 2] = off; off += v2; }
    if (base + 3 < n) { rowptr[base + 3] = off; off += v3; }
    if (blockIdx.x == 0 && tid == 0) rowptr[n] = partial[G];
}

// ---- launches ----
template <int MODE>
__global__ __launch_bounds__(256) void k_g32(const u16* __restrict__ feat,
                                             const int* __restrict__ rowptr,
                                             const int* __restrict__ col,
                                             const int* __restrict__ od,
                                             u16* __restrict__ out, int M) {
    dev_gather32<MODE>(feat, rowptr, col, od, out, M, blockIdx.x);
}

template <int MA, int MB>
__global__ __launch_bounds__(256) void k_g32x2(
    const u16* fA, const int* rpA, const int* oA, u16* outA, int MAr, int nbA,
    const u16* fB, const int* rpB, const int* oB, u16* outB, int MBr,
    const int* __restrict__ col) {
    if ((int)blockIdx.x < nbA) dev_gather32<MA>(fA, rpA, col, oA, outA, MAr, blockIdx.x);
    else                       dev_gather32<MB>(fB, rpB, col, oB, outB, MBr, blockIdx.x - nbA);
}

template <bool MASK>
__global__ __launch_bounds__(256) void k_mmd(const u16* __restrict__ Ap,
                                             const u16* __restrict__ Wtg,
                                             const float* __restrict__ bias,
                                             u16* __restrict__ out,
                                             const int* __restrict__ rowptr, int M) {
    dev_mmd<MASK>(Ap, Wtg, bias, out, rowptr, M, blockIdx.x);
}

__global__ __launch_bounds__(256) void k_mmd2(
    const u16* A1, const u16* Wt1, const float* b1, u16* o1, const int* rp1, int M1, int nb1,
    const u16* A2, const u16* Wt2, const float* b2, u16* o2, int M2) {
    if ((int)blockIdx.x < nb1) dev_mmd<true >(A1, Wt1, b1, o1, rp1, M1, blockIdx.x);
    else                       dev_mmd<false>(A2, Wt2, b2, o2, nullptr, M2, blockIdx.x - nb1);
}

// double matmul: out1 = A@Wt1+b1 (global + LDS), out2 = out1@Wt2+b2.
// Numerics identical to two kernels (out1 bf16-rounded before reuse).
__global__ __launch_bounds__(256) void k_mmdd(const u16* __restrict__ Ap,
                                              const u16* __restrict__ Wt1,
                                              const float* __restrict__ b1,
                                              u16* __restrict__ out1,
                                              const u16* __restrict__ Wt2,
                                              const float* __restrict__ b2,
                                              u16* __restrict__ out2, int M) {
    __shared__ u16 Gl[64 * AST];
    int tid = threadIdx.x;
    int wv = tid >> 6, lane = tid & 63, m16 = lane & 15, quad = lane >> 4;
    int m0 = (int)blockIdx.x * 64;
    int arow = m0 + wv * 16 + m16;
    if (arow >= M) arow = M - 1;
    const u16* Arow = Ap + (size_t)arow * F;

    f32x4 acc[8];
#pragma unroll
    for (int t = 0; t < 8; t++)
#pragma unroll
        for (int r = 0; r < 4; r++) acc[t][r] = 0.f;
#pragma unroll
    for (int k0 = 0; k0 < F; k0 += 32) {
        bf16x8 af = *(const bf16x8*)&Arow[k0 + quad * 8];
#pragma unroll
        for (int t = 0; t < 8; t++) {
            bf16x8 bf = *(const bf16x8*)&Wt1[(t * 16 + m16) * F + k0 + quad * 8];
            acc[t] = __builtin_amdgcn_mfma_f32_16x16x32_bf16(af, bf, acc[t], 0, 0, 0);
        }
    }
#pragma unroll
    for (int t = 0; t < 8; t++) {
#pragma unroll
        for (int r = 0; r < 4; r++) {
            int lr = wv * 16 + quad * 4 + r;
            int gr = m0 + lr;
            int gc = t * 16 + m16;
            u16 v = f2bf(acc[t][r] + b1[gc]);
            Gl[lr * AST + gc] = v;
            if (gr < M) out1[(size_t)gr * F + gc] = v;
        }
    }
    __syncthreads();

#pragma unroll
    for (int t = 0; t < 8; t++)
#pragma unroll
        for (int r = 0; r < 4; r++) acc[t][r] = 0.f;
#pragma unroll
    for (int k0 = 0; k0 < F; k0 += 32) {
        bf16x8 af = *(const bf16x8*)&Gl[(wv * 16 + m16) * AST + k0 + quad * 8];
#pragma unroll
        for (int t = 0; t < 8; t++) {
            bf16x8 bf = *(const bf16x8*)&Wt2[(t * 16 + m16) * F + k0 + quad * 8];
            acc[t] = __builtin_amdgcn_mfma_f32_16x16x32_bf16(af, bf, acc[t], 0, 0, 0);
        }
    }
#pragma unroll
    for (int t = 0; t < 8; t++) {
#pragma unroll
        for (int r = 0; r < 4; r++) {
            int gr = m0 + wv * 16 + quad * 4 + r;
            if (gr >= M) continue;
            int gc = t * 16 + m16;
            out2[(size_t)gr * F + gc] = f2bf(acc[t][r] + b2[gc]);
        }
    }
}

// masked mm (enc0) || big gcn gather (g0)
__global__ __launch_bounds__(256) void k_mmd_g32(
    const u16* A1, const u16* Wt1, const float* b1, u16* o1, const int* rp1, int M1, int nb1,
    const u16* feat, const int* rp2, const int* od2, u16* out2, int M2,
    const int* __restrict__ col) {
    if ((int)blockIdx.x < nb1) dev_mmd<true>(A1, Wt1, b1, o1, rp1, M1, blockIdx.x);
    else dev_gather32<1>(feat, rp2, col, od2, out2, M2, blockIdx.x - nb1);
}

// small gcn gather (g2) || big plain mm (g0's projection)
__global__ __launch_bounds__(256) void k_g32_mmd(
    const u16* feat, const int* rp1, const int* od1, u16* out1, int M1, int nb1,
    const u16* A2, const u16* Wt2, const float* b2, u16* o2, int M2,
    const int* __restrict__ col) {
    if ((int)blockIdx.x < nb1) dev_gather32<1>(feat, rp1, col, od1, out1, M1, blockIdx.x);
    else dev_mmd<false>(A2, Wt2, b2, o2, nullptr, M2, blockIdx.x - nb1);
}

// heads: head0 gathers d0 on the fly from dec1 CSR (D0 never materialized)
__global__ __launch_bounds__(256) void k_head3(
    const u16* Ga, const u16* dFeat, const int* rpD1, const int* colp,
    const float* Wa, const float* Ba, int nb0,
    const u16* Gb, const u16* Db, const float* Wb, const float* Bb, int nb1,
    const u16* Gc, const float* Wc, const float* Bc,
    float* __restrict__ out) {
    __shared__ char smem[1280 * 4 + 32];
    int b = blockIdx.x;
    if (b < nb0)            dev_head<true >(smem, Ga, dFeat, rpD1, colp, Wa, Ba, out, N0, b);
    else if (b < nb0 + nb1) dev_head<false>(smem, Gb, Db, nullptr, nullptr, Wb, Bb, out + (size_t)N0 * 5, N1, b - nb0);
    else                    dev_head<false>(smem, Gc, Gc, nullptr, nullptr, Wc, Bc, out + (size_t)(N0 + N1) * 5, N2, b - nb0 - nb1);
}

extern "C" void kernel_launch(void* const* d_in, const int* in_sizes, int n_in,
                              void* d_out, int out_size, void* d_ws, size_t ws_size,
                              hipStream_t stream) {
    const float* X = (const float*)d_in[0];
    const int *g0s = (const int*)d_in[1], *g0d = (const int*)d_in[2];
    const int *g1s = (const int*)d_in[3], *g1d = (const int*)d_in[4];
    const int *g2s = (const int*)d_in[5], *g2d = (const int*)d_in[6];
    const int *i0s = (const int*)d_in[7], *i0d = (const int*)d_in[8];
    const int *i1s = (const int*)d_in[9], *i1d = (const int*)d_in[10];
    const int *dc0s = (const int*)d_in[11], *dc0d = (const int*)d_in[12];
    const int *dc1s = (const int*)d_in[13], *dc1d = (const int*)d_in[14];
    const float *Wemb = (const float*)d_in[15], *bemb = (const float*)d_in[16];
    const float *Wg0 = (const float*)d_in[17], *bg0 = (const float*)d_in[18];
    const float *Wg1 = (const float*)d_in[19], *bg1 = (const float*)d_in[20];
    const float *Wg2 = (const float*)d_in[21], *bg2 = (const float*)d_in[22];
    const float *We0 = (const float*)d_in[23], *be0 = (const float*)d_in[24];
    const float *We1 = (const float*)d_in[25], *be1 = (const float*)d_in[26];
    const float *Wd0 = (const float*)d_in[27], *bd0 = (const float*)d_in[28];
    const float *Wd1 = (const float*)d_in[29], *bd1 = (const float*)d_in[30];
    const float *Wh0 = (const float*)d_in[31], *bh0 = (const float*)d_in[32];
    const float *Wh1 = (const float*)d_in[33], *bh1 = (const float*)d_in[34];
    const float *Wh2 = (const float*)d_in[35], *bh2 = (const float*)d_in[36];
    const int Eg0 = in_sizes[1], Eg1 = in_sizes[3], Eg2 = in_sizes[5];
    const int Ei0 = in_sizes[7], Ei1 = in_sizes[9];
    const int Ed0 = in_sizes[11], Ed1 = in_sizes[13];
    (void)n_in; (void)out_size; (void)ws_size;

    const int B_I0 = 0;
    const int B_I1 = B_I0 + N1;
    const int B_G2 = B_I1 + N2;
    const int B_D0 = B_G2 + N2;
    const int B_G1 = B_D0 + N1;
    const int B_G0 = B_G1 + N1;
    const int B_D1 = B_G0 + N0;
    const int NROWS = B_D1 + N0;                  // 287500
    const int ETOT  = Eg0 + Eg1 + Eg2 + Ei0 + Ei1 + Ed0 + Ed1;
    const int ETOTG = Eg0 + Eg1 + Eg2;
    const int OB_G0 = 0, OB_G1 = N0, OB_G2 = N0 + N1;
    const int NOD = N0 + N1 + N2;                 // 131250
    const int G = (NROWS + SCHUNK - 1) / SCHUNK;  // scan blocks (71)
    const int rowsPerWin = (NROWS + 7) / 8;
    const float invRow = 1.0f / (float)rowsPerWin;
    const int NCH = (ETOT + 256 * EPT - 1) / (256 * EPT);   // fill edge chunks

    char* wsb = (char*)d_ws;
    size_t off = 0;
    auto alloc = [&](size_t bytes) -> char* {
        char* p = wsb + off;
        off = (off + bytes + 255) & ~(size_t)255;
        return p;
    };
    u16* h0  = (u16*)alloc((size_t)N0 * F * 2);
    u16* h1  = (u16*)alloc((size_t)N1 * F * 2);
    u16* h2  = (u16*)alloc((size_t)N2 * F * 2);
    u16* G0  = (u16*)alloc((size_t)N0 * F * 2);
    u16* G1  = (u16*)alloc((size_t)N1 * F * 2);
    u16* G2  = (u16*)alloc((size_t)N2 * F * 2);
    u16* D1  = (u16*)alloc((size_t)N1 * F * 2);
    u16* agg = (u16*)alloc((size_t)N0 * F * 2);   // g0 gather out
    u16* bN1 = (u16*)alloc((size_t)N1 * F * 2);   // g1 gather out / dec1 proj
    u16* bN2 = (u16*)alloc((size_t)N2 * F * 2);   // i1/g2 gather out
    u16* pN2 = (u16*)alloc((size_t)N2 * F * 2);   // dec0 proj out
    u16* pA  = D1;                                // i0 gather out (D1 dead until L13)
    u16* WtAll = (u16*)alloc((size_t)7 * 16384 * 2);  // bf16 W^T x7
    int* cnt    = (int*)alloc((size_t)NROWS * 4);
    int* od     = (int*)alloc((size_t)NOD * 4);   // adjacent to cnt: one memset
    int* rowptr = (int*)alloc((size_t)(NROWS + 1) * 4);
    u16* occ    = (u16*)alloc((size_t)ETOT * 2);  // per-edge occurrence index
    int* col    = (int*)alloc((size_t)ETOT * 4);
    int* part   = (int*)alloc((size_t)(G + 1) * 4);
    float* out = (float*)d_out;

    // W^T order: We0, Wg0, We1, Wg1, Wg2, Wd0, Wd1
    u16* WtE0 = WtAll + 0 * 16384;
    u16* WtG0 = WtAll + 1 * 16384;
    u16* WtE1 = WtAll + 2 * 16384;
    u16* WtG1 = WtAll + 3 * 16384;
    u16* WtG2 = WtAll + 4 * 16384;
    u16* WtD0 = WtAll + 5 * 16384;
    u16* WtD1 = WtAll + 6 * 16384;
    W7 Wsrc;
    Wsrc.w[0] = We0; Wsrc.w[1] = Wg0; Wsrc.w[2] = We1; Wsrc.w[3] = Wg1;
    Wsrc.w[4] = Wg2; Wsrc.w[5] = Wd0; Wsrc.w[6] = Wd1;

    // segment table: inc0, inc1, g2, dec0, g1, g0, dec1
    Seg7 S;
    S.src[0] = i0s;  S.dst[0] = i0d;  S.cbase[0] = B_I0;
    S.src[1] = i1s;  S.dst[1] = i1d;  S.cbase[1] = B_I1;
    S.src[2] = g2s;  S.dst[2] = g2d;  S.cbase[2] = B_G2;
    S.src[3] = dc0s; S.dst[3] = dc0d; S.cbase[3] = B_D0;
    S.src[4] = g1s;  S.dst[4] = g1d;  S.cbase[4] = B_G1;
    S.src[5] = g0s;  S.dst[5] = g0d;  S.cbase[5] = B_G0;
    S.src[6] = dc1s; S.dst[6] = dc1d; S.cbase[6] = B_D1;
    {
        int Es[7] = {Ei0, Ei1, Eg2, Ed0, Eg1, Eg0, Ed1};
        int acc = 0;
        for (int i = 0; i < 7; i++) { acc += Es[i]; S.end[i] = acc; }
    }
    SegO SO;
    SO.src[0] = g0s; SO.obase[0] = OB_G0; SO.end[0] = Eg0;
    SO.src[1] = g1s; SO.obase[1] = OB_G1; SO.end[1] = Eg0 + Eg1;
    SO.src[2] = g2s; SO.obase[2] = OB_G2; SO.end[2] = Eg0 + Eg1 + Eg2;

    const int nbEmb   = (N0 + 63) / 64;                 // 1563
    const int nbPrep  = (7 * 16384) / 256;              // 448
    const int nbCnt   = (ETOT + 256 * CEPT - 1) / (256 * CEPT);
    const int nbOd    = (ETOTG + 256 * CEPT - 1) / (256 * CEPT);
    const int nbFill  = NCH * 8;

    // L1: emb mm | W^T prep | dst count | od count — all atomics in one launch
    hipMemsetAsync(cnt, 0, (size_t)((char*)od - (char*)cnt) + (size_t)NOD * 4, stream);
    k_count_emb<<<nbEmb + nbPrep + nbCnt + nbOd, 256, 0, stream>>>(
        S, SO, Wsrc, WtAll, cnt, od, occ, ETOT, ETOTG, X, Wemb, bemb, h0,
        nbEmb, nbPrep, nbCnt);
    // L2-L4: scan
    k_scan1<<<G, 1024, 0, stream>>>(cnt, part, NROWS);
    k_scan2<<<1, 128, 0, stream>>>(part, G);
    k_scan3<<<G, 1024, 0, stream>>>(cnt, part, rowptr, NROWS, G);
    // L5: pure windowed fill (no atomics)
    k_fill<<<nbFill, 256, 0, stream>>>(S, rowptr, occ, col, ETOT, invRow);

    // L6: i0 mean-gather (h0 -> pA)
    k_g32<0><<<(N1 * 32 + 255) / 256, 256, 0, stream>>>(h0, rowptr + B_I0, col, nullptr, pA, N1);
    // L7: mm enc0 (pA -> h1, masked) || g0 gcn-gather (h0 -> agg)
    {
        int nb1 = (N1 + 63) / 64;
        int nb2 = (N0 * 32 + 255) / 256;
        k_mmd_g32<<<nb1 + nb2, 256, 0, stream>>>(pA, WtE0, be0, h1, rowptr + B_I0, N1, nb1,
                                                 h0, rowptr + B_G0, od + OB_G0, agg, N0, col);
    }
    // L8: i1 mean-gather (h1 -> bN2) || g1 gcn-gather (h1 -> bN1)
    {
        int nbA = (N2 * 32 + 255) / 256, nbB = (N1 * 32 + 255) / 256;
        k_g32x2<0, 1><<<nbA + nbB, 256, 0, stream>>>(
            h1, rowptr + B_I1, nullptr, bN2, N2, nbA,
            h1, rowptr + B_G1, od + OB_G1, bN1, N1, col);
    }
    // L9: mm enc1 (bN2 -> h2, masked) || mm g1 (bN1 -> G1)
    {
        int nb1 = (N2 + 63) / 64, nb2 = (N1 + 63) / 64;
        k_mmd2<<<nb1 + nb2, 256, 0, stream>>>(bN2, WtE1, be1, h2, rowptr + B_I1, N2, nb1,
                                              bN1, WtG1, bg1, G1, N1);
    }
    // L10: g2 gcn-gather (h2 -> bN2) || mm g0 (agg -> G0)
    {
        int nb1 = (N2 * 32 + 255) / 256;
        int nb2 = (N0 + 63) / 64;
        k_g32_mmd<<<nb1 + nb2, 256, 0, stream>>>(h2, rowptr + B_G2, od + OB_G2, bN2, N2, nb1,
                                                 agg, WtG0, bg0, G0, N0, col);
    }
    // L11: double mm — G2 = bN2@Wg2+bg2 (global+LDS), pN2 = G2@Wd0+bd0
    k_mmdd<<<(N2 + 63) / 64, 256, 0, stream>>>(bN2, WtG2, bg2, G2, WtD0, bd0, pN2, N2);
    // L12: dec0 mean-gather (pN2 -> D1)
    k_g32<0><<<(N1 * 32 + 255) / 256, 256, 0, stream>>>(pN2, rowptr + B_D0, col, nullptr, D1, N1);
    // L13: mm dec1 (D1 -> bN1)
    k_mmd<false><<<(N1 + 63) / 64, 256, 0, stream>>>(D1, WtD1, bd1, bN1, nullptr, N1);
    // L14: heads fused; head0 gathers d0 from bN1 via dec1 CSR on the fly
    {
        int nb0 = (N0 + 31) / 32, nb1 = (N1 + 31) / 32, nb2 = (N2 + 31) / 32;
        k_head3<<<nb0 + nb1 + nb2, 256, 0, stream>>>(G0, bN1, rowptr + B_D1, col, Wh0, bh0, nb0,
                                                     G1, D1, Wh1, bh1, nb1,
                                                     G2, Wh2, bh2, out);
    }
}

// Round 19
// 674.082 us; speedup vs baseline: 1.1042x; 1.1042x over previous
//
#include <hip/hip_runtime.h>

#define F 128
static const int N0 = 100000, N1 = 25000, N2 = 6250;

typedef unsigned short u16;
typedef unsigned int   u32;
typedef __attribute__((ext_vector_type(8))) short bf16x8;
typedef __attribute__((ext_vector_type(4))) float f32x4;

__device__ __forceinline__ float bf2f(u16 u) {
    union { u32 i; float f; } v; v.i = ((u32)u) << 16; return v.f;
}
__device__ __forceinline__ u16 f2bf(float f) {
    u32 u = __float_as_uint(f);
    u += 0x7fff + ((u >> 16) & 1);   // RNE
    return (u16)(u >> 16);
}

// ---- segment table for fused edge-parallel kernels (7 graphs) ----
struct Seg7 {
    const int* src[7];
    const int* dst[7];
    int end[7];      // cumulative edge-count boundaries
    int cbase[7];    // row-segment base in concatenated cnt/rowptr
    int obase[7];    // out-degree segment base, -1 if not a GCN graph
};
struct W7 { const float* w[7]; };

#define EPT 4            // fill: edges per thread per chunk
#define CEPT 8           // count: edges per thread (8 independent atomic chains)
#define AST (F + 8)      // LDS A-tile stride (u16)
#define SM32  (64*(32+8)*2 + 128*(32+8)*2 + 128*4)

// ================= device bodies =================

// small-K dense MFMA matmul (K=32, fp32 A: the embedding) — W staged in LDS
__device__ __forceinline__ void dev_mm32(char* smem, const float* __restrict__ Ap,
                                         const float* __restrict__ W,
                                         const float* __restrict__ bias,
                                         u16* __restrict__ out, int M, int blk) {
    const int K = 32;
    const int KST = K + 8;
    u16* Al = (u16*)smem;
    u16* Wt = (u16*)(smem + 64 * KST * 2);
    float* bl = (float*)(smem + 64 * KST * 2 + 128 * KST * 2);
    int tid = threadIdx.x;
    int m0 = blk * 64;

    for (int i = tid; i < K * 128; i += 256) {
        int k = i >> 7, n = i & 127;
        Wt[n * KST + k] = f2bf(W[i]);
    }
    for (int i = tid; i < 64 * K; i += 256) {
        int r = i / K, c = i % K;
        int gr = m0 + r;
        Al[r * KST + c] = (gr < M) ? f2bf(Ap[(size_t)gr * K + c]) : (u16)0;
    }
    if (tid < 128) bl[tid] = bias[tid];
    __syncthreads();

    int w = tid >> 6, lane = tid & 63, m16 = lane & 15, quad = lane >> 4;
    f32x4 acc[8];
#pragma unroll
    for (int t = 0; t < 8; t++)
#pragma unroll
        for (int r = 0; r < 4; r++) acc[t][r] = 0.f;

    {
        bf16x8 af = *(const bf16x8*)&Al[(w * 16 + m16) * KST + quad * 8];
#pragma unroll
        for (int t = 0; t < 8; t++) {
            bf16x8 bf = *(const bf16x8*)&Wt[(t * 16 + m16) * KST + quad * 8];
            acc[t] = __builtin_amdgcn_mfma_f32_16x16x32_bf16(af, bf, acc[t], 0, 0, 0);
        }
    }
#pragma unroll
    for (int t = 0; t < 8; t++) {
#pragma unroll
        for (int r = 0; r < 4; r++) {
            int gr = m0 + w * 16 + quad * 4 + r;
            if (gr >= M) continue;
            int gc = t * 16 + m16;
            out[(size_t)gr * F + gc] = f2bf(acc[t][r] + bl[gc]);
        }
    }
}

// LDS-free K=128 matmul: A-fragments straight from global (row clamped; rows
// past M never written), B-fragments from global bf16 W^T (L1-resident).
template <bool MASK>
__device__ __forceinline__ void dev_mmd(const u16* __restrict__ Ap,
                                        const u16* __restrict__ Wtg,
                                        const float* __restrict__ bias,
                                        u16* __restrict__ out,
                                        const int* __restrict__ rowptr,
                                        int M, int blk) {
    int tid = threadIdx.x;
    int wv = tid >> 6, lane = tid & 63, m16 = lane & 15, quad = lane >> 4;
    int m0 = blk * 64;
    int arow = m0 + wv * 16 + m16;
    if (arow >= M) arow = M - 1;
    const u16* Arow = Ap + (size_t)arow * F;

    f32x4 acc[8];
#pragma unroll
    for (int t = 0; t < 8; t++)
#pragma unroll
        for (int r = 0; r < 4; r++) acc[t][r] = 0.f;

#pragma unroll
    for (int k0 = 0; k0 < F; k0 += 32) {
        bf16x8 af = *(const bf16x8*)&Arow[k0 + quad * 8];
#pragma unroll
        for (int t = 0; t < 8; t++) {
            bf16x8 bf = *(const bf16x8*)&Wtg[(t * 16 + m16) * F + k0 + quad * 8];
            acc[t] = __builtin_amdgcn_mfma_f32_16x16x32_bf16(af, bf, acc[t], 0, 0, 0);
        }
    }
#pragma unroll
    for (int t = 0; t < 8; t++) {
#pragma unroll
        for (int r = 0; r < 4; r++) {
            int gr = m0 + wv * 16 + quad * 4 + r;
            if (gr >= M) continue;
            int gc = t * 16 + m16;
            bool zrow = false;
            if (MASK) zrow = (rowptr[gr + 1] == rowptr[gr]);
            float v = acc[t][r] + bias[gc];
            out[(size_t)gr * F + gc] = zrow ? (u16)0 : f2bf(v);
        }
    }
}

// 32-lane-group CSR gather: 2 rows/wave, ushort4/lane, 8-wide unroll.
// MODE 0: mean; MODE 1: gcn (rsqrt0(od[col]) inline)
template <int MODE>
__device__ __forceinline__ void dev_gather32(const u16* __restrict__ feat,
                                             const int* __restrict__ rowptr,
                                             const int* __restrict__ col,
                                             const int* __restrict__ od,
                                             u16* __restrict__ out, int M, int blk) {
    int row = (blk * 256 + (int)threadIdx.x) >> 5;
    if (row >= M) return;
    int l32 = threadIdx.x & 31;
    int fo = l32 << 2;
    int beg = rowptr[row], end = rowptr[row + 1];
    float a0 = 0.f, a1 = 0.f, a2 = 0.f, a3 = 0.f;
    int j = beg;
    for (; j + 8 <= end; j += 8) {
        int cc[8];
#pragma unroll
        for (int t = 0; t < 8; t++) cc[t] = col[j + t];
        float ss[8];
#pragma unroll
        for (int t = 0; t < 8; t++) {
            if (MODE == 1) { int o = od[cc[t]]; ss[t] = o > 0 ? rsqrtf((float)o) : 0.f; }
            else ss[t] = 1.f;
        }
        ushort4 uu[8];
#pragma unroll
        for (int t = 0; t < 8; t++) uu[t] = *(const ushort4*)&feat[(size_t)cc[t] * F + fo];
#pragma unroll
        for (int t = 0; t < 8; t++) {
            a0 += bf2f(uu[t].x) * ss[t]; a1 += bf2f(uu[t].y) * ss[t];
            a2 += bf2f(uu[t].z) * ss[t]; a3 += bf2f(uu[t].w) * ss[t];
        }
    }
    for (; j < end; j++) {
        int c = col[j];
        float s = 1.f;
        if (MODE == 1) { int o = od[c]; s = o > 0 ? rsqrtf((float)o) : 0.f; }
        ushort4 u = *(const ushort4*)&feat[(size_t)c * F + fo];
        a0 += bf2f(u.x) * s; a1 += bf2f(u.y) * s;
        a2 += bf2f(u.z) * s; a3 += bf2f(u.w) * s;
    }
    int deg = end - beg;
    float fs = (MODE == 0) ? (deg > 0 ? 1.f / (float)deg : 0.f)
                           : (deg > 0 ? rsqrtf((float)deg) : 0.f);
    ushort4 o;
    o.x = f2bf(a0 * fs); o.y = f2bf(a1 * fs);
    o.z = f2bf(a2 * fs); o.w = f2bf(a3 * fs);
    *(ushort4*)&out[(size_t)row * F + fo] = o;
}

// head body, 32-lane groups: softmax(concat(g,d)@Wh+bh) -> fp32.
// GD: d-row gathered on the fly (mean over CSR, ushort4 lanes).
template <bool GD>
__device__ __forceinline__ void dev_head(char* smem, const u16* __restrict__ g,
                                         const u16* __restrict__ d,
                                         const int* __restrict__ rowptr,
                                         const int* __restrict__ col,
                                         const float* __restrict__ Wh,
                                         const float* __restrict__ bh,
                                         float* __restrict__ out, int M, int blk) {
    float* Wl = (float*)smem;          // 1280
    float* bl = (float*)(smem + 1280 * 4);
    int tid = threadIdx.x;
    for (int i = tid; i < 1280; i += 256) Wl[i] = Wh[i];
    if (tid < 5) bl[tid] = bh[tid];
    __syncthreads();

    int grp = tid >> 5;
    int l32 = tid & 31;
    int k0 = l32 << 2;
    for (int i = 0; i < 4; i++) {
        int row = blk * 32 + grp * 4 + i;
        if (row < M) {
            float dv[4];
            if (GD) {
                int beg = rowptr[row], end = rowptr[row + 1];
                dv[0] = dv[1] = dv[2] = dv[3] = 0.f;
                int j = beg;
                for (; j + 4 <= end; j += 4) {
                    int c0 = col[j], c1 = col[j + 1], c2 = col[j + 2], c3 = col[j + 3];
                    ushort4 u0 = *(const ushort4*)&d[(size_t)c0 * F + k0];
                    ushort4 u1 = *(const ushort4*)&d[(size_t)c1 * F + k0];
                    ushort4 u2 = *(const ushort4*)&d[(size_t)c2 * F + k0];
                    ushort4 u3 = *(const ushort4*)&d[(size_t)c3 * F + k0];
                    dv[0] += bf2f(u0.x) + bf2f(u1.x) + bf2f(u2.x) + bf2f(u3.x);
                    dv[1] += bf2f(u0.y) + bf2f(u1.y) + bf2f(u2.y) + bf2f(u3.y);
                    dv[2] += bf2f(u0.z) + bf2f(u1.z) + bf2f(u2.z) + bf2f(u3.z);
                    dv[3] += bf2f(u0.w) + bf2f(u1.w) + bf2f(u2.w) + bf2f(u3.w);
                }
                for (; j < end; j++) {
                    int c = col[j];
                    ushort4 u = *(const ushort4*)&d[(size_t)c * F + k0];
                    dv[0] += bf2f(u.x); dv[1] += bf2f(u.y);
                    dv[2] += bf2f(u.z); dv[3] += bf2f(u.w);
                }
                int deg = end - beg;
                float fs = deg > 0 ? 1.f / (float)deg : 0.f;
#pragma unroll
                for (int q = 0; q < 4; q++) dv[q] *= fs;
            } else {
                ushort4 du = *(const ushort4*)&d[(size_t)row * F + k0];
                dv[0] = bf2f(du.x); dv[1] = bf2f(du.y);
                dv[2] = bf2f(du.z); dv[3] = bf2f(du.w);
            }
            ushort4 gu = *(const ushort4*)&g[(size_t)row * F + k0];
            float gv[4] = {bf2f(gu.x), bf2f(gu.y), bf2f(gu.z), bf2f(gu.w)};
            float p[5];
#pragma unroll
            for (int o = 0; o < 5; o++) {
                float v = 0.f;
#pragma unroll
                for (int q = 0; q < 4; q++)
                    v += gv[q] * Wl[(k0 + q) * 5 + o] + dv[q] * Wl[(k0 + q + 128) * 5 + o];
                p[o] = v;
            }
#pragma unroll
            for (int o = 0; o < 5; o++) {
                float v = p[o];
                v += __shfl_xor(v, 16, 64);
                v += __shfl_xor(v, 8, 64);
                v += __shfl_xor(v, 4, 64);
                v += __shfl_xor(v, 2, 64);
                v += __shfl_xor(v, 1, 64);
                p[o] = v + bl[o];
            }
            if (l32 == 0) {
                float m = p[0];
#pragma unroll
                for (int o = 1; o < 5; o++) m = fmaxf(m, p[o]);
                float e[5], s = 0.f;
#pragma unroll
                for (int o = 0; o < 5; o++) { e[o] = expf(p[o] - m); s += e[o]; }
                float inv = 1.f / s;
#pragma unroll
                for (int o = 0; o < 5; o++) out[(size_t)row * 5 + o] = e[o] * inv;
            }
        }
    }
}

// ================= kernels =================

// L1: three roles — emb matmul | W^T prep | dst histogram (return-atomics,
// CEPT=8 pipelined chains; emits occ). od deliberately NOT here: R18 measured
// that od contends with the return-atomic stream (+115 µs); it lives in fill
// where it overlaps the L2 col-store path (R17 arrangement, best measured).
__global__ __launch_bounds__(256) void k_count_emb(Seg7 S, W7 Wsrc,
                                                   u16* __restrict__ WtAll,
                                                   int* __restrict__ cnt,
                                                   u16* __restrict__ occ, int ETOT,
                                                   const float* __restrict__ X,
                                                   const float* __restrict__ Wemb,
                                                   const float* __restrict__ bemb,
                                                   u16* __restrict__ h0,
                                                   int nbMM, int nbPrep) {
    __shared__ char smem[SM32];
    int blk = blockIdx.x;
    if (blk < nbMM) {
        dev_mm32(smem, X, Wemb, bemb, h0, N0, blk);
        return;
    }
    if (blk < nbMM + nbPrep) {
        int g = (blk - nbMM) * 256 + threadIdx.x;   // < 7*16384
        int m = g >> 14, idx = g & 16383;
        int n = idx >> 7, k = idx & 127;
        WtAll[g] = f2bf(Wsrc.w[m][k * 128 + n]);    // coalesced writes
        return;
    }
    int base = (blk - nbMM - nbPrep) * (256 * CEPT) + threadIdx.x;
    int ee[CEPT], grow[CEPT];
#pragma unroll
    for (int t = 0; t < CEPT; t++) {
        int e = base + t * 256;
        ee[t] = e;
        grow[t] = -1;
        if (e < ETOT) {
            int s = 0;
            while (e >= S.end[s]) s++;
            int le = e - ((s == 0) ? 0 : S.end[s - 1]);
            grow[t] = S.cbase[s] + S.dst[s][le];
        }
    }
    u32 r[CEPT];
#pragma unroll
    for (int t = 0; t < CEPT; t++)
        if (grow[t] >= 0) r[t] = atomicAdd((u32*)&cnt[grow[t]], 1u);
#pragma unroll
    for (int t = 0; t < CEPT; t++)
        if (grow[t] >= 0) occ[ee[t]] = (u16)r[t];
}

// L5: atomic-free XCD-windowed CSR fill (pos = rowptr[row] + occ[e]) + od hist
// (od atomics overlap the col-store path — R17's proven placement)
__global__ __launch_bounds__(256) void k_fill_od(Seg7 S,
                                                 const int* __restrict__ rowptr,
                                                 const u16* __restrict__ occ,
                                                 int* __restrict__ col,
                                                 int* __restrict__ od, int ETOT,
                                                 float invRow, float invOd) {
    int win = blockIdx.x & 7;
    int base = ((int)blockIdx.x >> 3) * (256 * EPT) + threadIdx.x;
#pragma unroll
    for (int t = 0; t < EPT; t++) {
        int e = base + t * 256;
        if (e >= ETOT) break;
        int s = 0;
        while (e >= S.end[s]) s++;
        int le = e - ((s == 0) ? 0 : S.end[s - 1]);
        int grow = S.cbase[s] + S.dst[s][le];
        int w1 = (int)((float)grow * invRow); w1 = w1 > 7 ? 7 : w1;
        int sv = -1;
        if (w1 == win || S.obase[s] >= 0) sv = S.src[s][le];
        if (w1 == win) col[rowptr[grow] + (int)occ[e]] = sv;
        if (S.obase[s] >= 0) {
            int gs = S.obase[s] + sv;
            int w2 = (int)((float)gs * invOd); w2 = w2 > 7 ? 7 : w2;
            if (w2 == win) atomicAdd(&od[gs], 1);
        }
    }
}

// ---- multi-block exclusive scan over concatenated counts (3 phases) ----
#define SCHUNK 4096  // 1024 threads x 4
__global__ __launch_bounds__(1024) void k_scan1(const int* __restrict__ cnt,
                                                int* __restrict__ partial, int n) {
    __shared__ int red[1024];
    int tid = threadIdx.x;
    int base = blockIdx.x * SCHUNK + tid * 4;
    int s = 0;
#pragma unroll
    for (int j = 0; j < 4; j++) { int i = base + j; if (i < n) s += cnt[i]; }
    red[tid] = s;
    __syncthreads();
    for (int d = 512; d > 0; d >>= 1) {
        if (tid < d) red[tid] += red[tid + d];
        __syncthreads();
    }
    if (tid == 0) partial[blockIdx.x] = red[0];
}

__global__ __launch_bounds__(128) void k_scan2(int* __restrict__ partial, int G) {
    __shared__ int sh[128];
    int tid = threadIdx.x;
    sh[tid] = (tid < G) ? partial[tid] : 0;
    __syncthreads();
    for (int d = 1; d < 128; d <<= 1) {
        int t = (tid >= d) ? sh[tid - d] : 0;
        __syncthreads();
        sh[tid] += t;
        __syncthreads();
    }
    if (tid < G) partial[tid] = (tid > 0) ? sh[tid - 1] : 0;  // exclusive
    if (tid == 127) partial[G] = sh[127];                     // grand total
}

__global__ __launch_bounds__(1024) void k_scan3(const int* __restrict__ cnt,
                                                const int* __restrict__ partial,
                                                int* __restrict__ rowptr,
                                                int n, int G) {
    __shared__ int red[1024];
    int tid = threadIdx.x;
    int base = blockIdx.x * SCHUNK + tid * 4;
    int v0 = 0, v1 = 0, v2 = 0, v3 = 0;
    if (base + 0 < n) v0 = cnt[base + 0];
    if (base + 1 < n) v1 = cnt[base + 1];
    if (base + 2 < n) v2 = cnt[base + 2];
    if (base + 3 < n) v3 = cnt[base + 3];
    red[tid] = v0 + v1 + v2 + v3;
    __syncthreads();
    for (int d = 1; d < 1024; d <<= 1) {
        int t = (tid >= d) ? red[tid - d] : 0;
        __syncthreads();
        red[tid] += t;
        __syncthreads();
    }
    int off = partial[blockIdx.x] + ((tid > 0) ? red[tid - 1] : 0);
    if (base + 0 < n) { rowptr[base + 0] = off; off += v0; }
    if (base + 1 < n) { rowptr[base + 1] = off; off += v1; }
    if (base + 2 < n) { rowptr[base + 2] = off; off += v2; }
    if (base + 3 < n) { rowptr[base + 3] = off; off += v3; }
    if (blockIdx.x == 0 && tid == 0) rowptr[n] = partial[G];
}

// ---- launches ----
template <int MODE>
__global__ __launch_bounds__(256) void k_g32(const u16* __restrict__ feat,
                                             const int* __restrict__ rowptr,
                                             const int* __restrict__ col,
                                             const int* __restrict__ od,
                                             u16* __restrict__ out, int M) {
    dev_gather32<MODE>(feat, rowptr, col, od, out, M, blockIdx.x);
}

template <int MA, int MB>
__global__ __launch_bounds__(256) void k_g32x2(
    const u16* fA, const int* rpA, const int* oA, u16* outA, int MAr, int nbA,
    const u16* fB, const int* rpB, const int* oB, u16* outB, int MBr,
    const int* __restrict__ col) {
    if ((int)blockIdx.x < nbA) dev_gather32<MA>(fA, rpA, col, oA, outA, MAr, blockIdx.x);
    else                       dev_gather32<MB>(fB, rpB, col, oB, outB, MBr, blockIdx.x - nbA);
}

template <bool MASK>
__global__ __launch_bounds__(256) void k_mmd(const u16* __restrict__ Ap,
                                             const u16* __restrict__ Wtg,
                                             const float* __restrict__ bias,
                                             u16* __restrict__ out,
                                             const int* __restrict__ rowptr, int M) {
    dev_mmd<MASK>(Ap, Wtg, bias, out, rowptr, M, blockIdx.x);
}

__global__ __launch_bounds__(256) void k_mmd2(
    const u16* A1, const u16* Wt1, const float* b1, u16* o1, const int* rp1, int M1, int nb1,
    const u16* A2, const u16* Wt2, const float* b2, u16* o2, int M2) {
    if ((int)blockIdx.x < nb1) dev_mmd<true >(A1, Wt1, b1, o1, rp1, M1, blockIdx.x);
    else                       dev_mmd<false>(A2, Wt2, b2, o2, nullptr, M2, blockIdx.x - nb1);
}

// double matmul: out1 = A@Wt1+b1 (global + LDS), out2 = out1@Wt2+b2.
// Numerics identical to two kernels (out1 bf16-rounded before reuse).
__global__ __launch_bounds__(256) void k_mmdd(const u16* __restrict__ Ap,
                                              const u16* __restrict__ Wt1,
                                              const float* __restrict__ b1,
                                              u16* __restrict__ out1,
                                              const u16* __restrict__ Wt2,
                                              const float* __restrict__ b2,
                                              u16* __restrict__ out2, int M) {
    __shared__ u16 Gl[64 * AST];
    int tid = threadIdx.x;
    int wv = tid >> 6, lane = tid & 63, m16 = lane & 15, quad = lane >> 4;
    int m0 = (int)blockIdx.x * 64;
    int arow = m0 + wv * 16 + m16;
    if (arow >= M) arow = M - 1;
    const u16* Arow = Ap + (size_t)arow * F;

    f32x4 acc[8];
#pragma unroll
    for (int t = 0; t < 8; t++)
#pragma unroll
        for (int r = 0; r < 4; r++) acc[t][r] = 0.f;
#pragma unroll
    for (int k0 = 0; k0 < F; k0 += 32) {
        bf16x8 af = *(const bf16x8*)&Arow[k0 + quad * 8];
#pragma unroll
        for (int t = 0; t < 8; t++) {
            bf16x8 bf = *(const bf16x8*)&Wt1[(t * 16 + m16) * F + k0 + quad * 8];
            acc[t] = __builtin_amdgcn_mfma_f32_16x16x32_bf16(af, bf, acc[t], 0, 0, 0);
        }
    }
#pragma unroll
    for (int t = 0; t < 8; t++) {
#pragma unroll
        for (int r = 0; r < 4; r++) {
            int lr = wv * 16 + quad * 4 + r;
            int gr = m0 + lr;
            int gc = t * 16 + m16;
            u16 v = f2bf(acc[t][r] + b1[gc]);
            Gl[lr * AST + gc] = v;
            if (gr < M) out1[(size_t)gr * F + gc] = v;
        }
    }
    __syncthreads();

#pragma unroll
    for (int t = 0; t < 8; t++)
#pragma unroll
        for (int r = 0; r < 4; r++) acc[t][r] = 0.f;
#pragma unroll
    for (int k0 = 0; k0 < F; k0 += 32) {
        bf16x8 af = *(const bf16x8*)&Gl[(wv * 16 + m16) * AST + k0 + quad * 8];
#pragma unroll
        for (int t = 0; t < 8; t++) {
            bf16x8 bf = *(const bf16x8*)&Wt2[(t * 16 + m16) * F + k0 + quad * 8];
            acc[t] = __builtin_amdgcn_mfma_f32_16x16x32_bf16(af, bf, acc[t], 0, 0, 0);
        }
    }
#pragma unroll
    for (int t = 0; t < 8; t++) {
#pragma unroll
        for (int r = 0; r < 4; r++) {
            int gr = m0 + wv * 16 + quad * 4 + r;
            if (gr >= M) continue;
            int gc = t * 16 + m16;
            out2[(size_t)gr * F + gc] = f2bf(acc[t][r] + b2[gc]);
        }
    }
}

// masked mm (enc0) || big gcn gather (g0)
__global__ __launch_bounds__(256) void k_mmd_g32(
    const u16* A1, const u16* Wt1, const float* b1, u16* o1, const int* rp1, int M1, int nb1,
    const u16* feat, const int* rp2, const int* od2, u16* out2, int M2,
    const int* __restrict__ col) {
    if ((int)blockIdx.x < nb1) dev_mmd<true>(A1, Wt1, b1, o1, rp1, M1, blockIdx.x);
    else dev_gather32<1>(feat, rp2, col, od2, out2, M2, blockIdx.x - nb1);
}

// small gcn gather (g2) || big plain mm (g0's projection)
__global__ __launch_bounds__(256) void k_g32_mmd(
    const u16* feat, const int* rp1, const int* od1, u16* out1, int M1, int nb1,
    const u16* A2, const u16* Wt2, const float* b2, u16* o2, int M2,
    const int* __restrict__ col) {
    if ((int)blockIdx.x < nb1) dev_gather32<1>(feat, rp1, col, od1, out1, M1, blockIdx.x);
    else dev_mmd<false>(A2, Wt2, b2, o2, nullptr, M2, blockIdx.x - nb1);
}

// heads: head0 gathers d0 on the fly from dec1 CSR (D0 never materialized)
__global__ __launch_bounds__(256) void k_head3(
    const u16* Ga, const u16* dFeat, const int* rpD1, const int* colp,
    const float* Wa, const float* Ba, int nb0,
    const u16* Gb, const u16* Db, const float* Wb, const float* Bb, int nb1,
    const u16* Gc, const float* Wc, const float* Bc,
    float* __restrict__ out) {
    __shared__ char smem[1280 * 4 + 32];
    int b = blockIdx.x;
    if (b < nb0)            dev_head<true >(smem, Ga, dFeat, rpD1, colp, Wa, Ba, out, N0, b);
    else if (b < nb0 + nb1) dev_head<false>(smem, Gb, Db, nullptr, nullptr, Wb, Bb, out + (size_t)N0 * 5, N1, b - nb0);
    else                    dev_head<false>(smem, Gc, Gc, nullptr, nullptr, Wc, Bc, out + (size_t)(N0 + N1) * 5, N2, b - nb0 - nb1);
}

extern "C" void kernel_launch(void* const* d_in, const int* in_sizes, int n_in,
                              void* d_out, int out_size, void* d_ws, size_t ws_size,
                              hipStream_t stream) {
    const float* X = (const float*)d_in[0];
    const int *g0s = (const int*)d_in[1], *g0d = (const int*)d_in[2];
    const int *g1s = (const int*)d_in[3], *g1d = (const int*)d_in[4];
    const int *g2s = (const int*)d_in[5], *g2d = (const int*)d_in[6];
    const int *i0s = (const int*)d_in[7], *i0d = (const int*)d_in[8];
    const int *i1s = (const int*)d_in[9], *i1d = (const int*)d_in[10];
    const int *dc0s = (const int*)d_in[11], *dc0d = (const int*)d_in[12];
    const int *dc1s = (const int*)d_in[13], *dc1d = (const int*)d_in[14];
    const float *Wemb = (const float*)d_in[15], *bemb = (const float*)d_in[16];
    const float *Wg0 = (const float*)d_in[17], *bg0 = (const float*)d_in[18];
    const float *Wg1 = (const float*)d_in[19], *bg1 = (const float*)d_in[20];
    const float *Wg2 = (const float*)d_in[21], *bg2 = (const float*)d_in[22];
    const float *We0 = (const float*)d_in[23], *be0 = (const float*)d_in[24];
    const float *We1 = (const float*)d_in[25], *be1 = (const float*)d_in[26];
    const float *Wd0 = (const float*)d_in[27], *bd0 = (const float*)d_in[28];
    const float *Wd1 = (const float*)d_in[29], *bd1 = (const float*)d_in[30];
    const float *Wh0 = (const float*)d_in[31], *bh0 = (const float*)d_in[32];
    const float *Wh1 = (const float*)d_in[33], *bh1 = (const float*)d_in[34];
    const float *Wh2 = (const float*)d_in[35], *bh2 = (const float*)d_in[36];
    const int Eg0 = in_sizes[1], Eg1 = in_sizes[3], Eg2 = in_sizes[5];
    const int Ei0 = in_sizes[7], Ei1 = in_sizes[9];
    const int Ed0 = in_sizes[11], Ed1 = in_sizes[13];
    (void)n_in; (void)out_size; (void)ws_size;

    const int B_I0 = 0;
    const int B_I1 = B_I0 + N1;
    const int B_G2 = B_I1 + N2;
    const int B_D0 = B_G2 + N2;
    const int B_G1 = B_D0 + N1;
    const int B_G0 = B_G1 + N1;
    const int B_D1 = B_G0 + N0;
    const int NROWS = B_D1 + N0;                  // 287500
    const int ETOT  = Eg0 + Eg1 + Eg2 + Ei0 + Ei1 + Ed0 + Ed1;
    const int OB_G0 = 0, OB_G1 = N0, OB_G2 = N0 + N1;
    const int NOD = N0 + N1 + N2;                 // 131250
    const int G = (NROWS + SCHUNK - 1) / SCHUNK;  // scan blocks (71)
    const int rowsPerWin = (NROWS + 7) / 8;
    const int odPerWin   = (NOD + 7) / 8;
    const float invRow = 1.0f / (float)rowsPerWin;
    const float invOd  = 1.0f / (float)odPerWin;
    const int NCH = (ETOT + 256 * EPT - 1) / (256 * EPT);   // fill edge chunks

    char* wsb = (char*)d_ws;
    size_t off = 0;
    auto alloc = [&](size_t bytes) -> char* {
        char* p = wsb + off;
        off = (off + bytes + 255) & ~(size_t)255;
        return p;
    };
    u16* h0  = (u16*)alloc((size_t)N0 * F * 2);
    u16* h1  = (u16*)alloc((size_t)N1 * F * 2);
    u16* h2  = (u16*)alloc((size_t)N2 * F * 2);
    u16* G0  = (u16*)alloc((size_t)N0 * F * 2);
    u16* G1  = (u16*)alloc((size_t)N1 * F * 2);
    u16* G2  = (u16*)alloc((size_t)N2 * F * 2);
    u16* D1  = (u16*)alloc((size_t)N1 * F * 2);
    u16* agg = (u16*)alloc((size_t)N0 * F * 2);   // g0 gather out
    u16* bN1 = (u16*)alloc((size_t)N1 * F * 2);   // g1 gather out / dec1 proj
    u16* bN2 = (u16*)alloc((size_t)N2 * F * 2);   // i1/g2 gather out
    u16* pN2 = (u16*)alloc((size_t)N2 * F * 2);   // dec0 proj out
    u16* pA  = D1;                                // i0 gather out (D1 dead until L12)
    u16* WtAll = (u16*)alloc((size_t)7 * 16384 * 2);  // bf16 W^T x7
    int* cnt    = (int*)alloc((size_t)NROWS * 4);
    int* od     = (int*)alloc((size_t)NOD * 4);   // adjacent to cnt: one memset
    int* rowptr = (int*)alloc((size_t)(NROWS + 1) * 4);
    u16* occ    = (u16*)alloc((size_t)ETOT * 2);  // per-edge occurrence index
    int* col    = (int*)alloc((size_t)ETOT * 4);
    int* part   = (int*)alloc((size_t)(G + 1) * 4);
    float* out = (float*)d_out;

    // W^T order: We0, Wg0, We1, Wg1, Wg2, Wd0, Wd1
    u16* WtE0 = WtAll + 0 * 16384;
    u16* WtG0 = WtAll + 1 * 16384;
    u16* WtE1 = WtAll + 2 * 16384;
    u16* WtG1 = WtAll + 3 * 16384;
    u16* WtG2 = WtAll + 4 * 16384;
    u16* WtD0 = WtAll + 5 * 16384;
    u16* WtD1 = WtAll + 6 * 16384;
    W7 Wsrc;
    Wsrc.w[0] = We0; Wsrc.w[1] = Wg0; Wsrc.w[2] = We1; Wsrc.w[3] = Wg1;
    Wsrc.w[4] = Wg2; Wsrc.w[5] = Wd0; Wsrc.w[6] = Wd1;

    // segment table: inc0, inc1, g2, dec0, g1, g0, dec1
    Seg7 S;
    S.src[0] = i0s;  S.dst[0] = i0d;  S.cbase[0] = B_I0; S.obase[0] = -1;
    S.src[1] = i1s;  S.dst[1] = i1d;  S.cbase[1] = B_I1; S.obase[1] = -1;
    S.src[2] = g2s;  S.dst[2] = g2d;  S.cbase[2] = B_G2; S.obase[2] = OB_G2;
    S.src[3] = dc0s; S.dst[3] = dc0d; S.cbase[3] = B_D0; S.obase[3] = -1;
    S.src[4] = g1s;  S.dst[4] = g1d;  S.cbase[4] = B_G1; S.obase[4] = OB_G1;
    S.src[5] = g0s;  S.dst[5] = g0d;  S.cbase[5] = B_G0; S.obase[5] = OB_G0;
    S.src[6] = dc1s; S.dst[6] = dc1d; S.cbase[6] = B_D1; S.obase[6] = -1;
    {
        int Es[7] = {Ei0, Ei1, Eg2, Ed0, Eg1, Eg0, Ed1};
        int acc = 0;
        for (int i = 0; i < 7; i++) { acc += Es[i]; S.end[i] = acc; }
    }

    const int nbEmb   = (N0 + 63) / 64;                 // 1563
    const int nbPrep  = (7 * 16384) / 256;              // 448
    const int nbCount = (ETOT + 256 * CEPT - 1) / (256 * CEPT);
    const int nbFill  = NCH * 8;

    // L1: emb mm | W^T prep | dst count (pipelined return-atomics, emits occ)
    hipMemsetAsync(cnt, 0, (size_t)((char*)od - (char*)cnt) + (size_t)NOD * 4, stream);
    k_count_emb<<<nbEmb + nbPrep + nbCount, 256, 0, stream>>>(
        S, Wsrc, WtAll, cnt, occ, ETOT, X, Wemb, bemb, h0, nbEmb, nbPrep);
    // L2-L4: scan
    k_scan1<<<G, 1024, 0, stream>>>(cnt, part, NROWS);
    k_scan2<<<1, 128, 0, stream>>>(part, G);
    k_scan3<<<G, 1024, 0, stream>>>(cnt, part, rowptr, NROWS, G);
    // L5: atomic-free windowed fill + od histogram
    k_fill_od<<<nbFill, 256, 0, stream>>>(S, rowptr, occ, col, od, ETOT, invRow, invOd);

    // L6: i0 mean-gather (h0 -> pA)
    k_g32<0><<<(N1 * 32 + 255) / 256, 256, 0, stream>>>(h0, rowptr + B_I0, col, nullptr, pA, N1);
    // L7: mm enc0 (pA -> h1, masked) || g0 gcn-gather (h0 -> agg)
    {
        int nb1 = (N1 + 63) / 64;
        int nb2 = (N0 * 32 + 255) / 256;
        k_mmd_g32<<<nb1 + nb2, 256, 0, stream>>>(pA, WtE0, be0, h1, rowptr + B_I0, N1, nb1,
                                                 h0, rowptr + B_G0, od + OB_G0, agg, N0, col);
    }
    // L8: i1 mean-gather (h1 -> bN2) || g1 gcn-gather (h1 -> bN1)
    {
        int nbA = (N2 * 32 + 255) / 256, nbB = (N1 * 32 + 255) / 256;
        k_g32x2<0, 1><<<nbA + nbB, 256, 0, stream>>>(
            h1, rowptr + B_I1, nullptr, bN2, N2, nbA,
            h1, rowptr + B_G1, od + OB_G1, bN1, N1, col);
    }
    // L9: mm enc1 (bN2 -> h2, masked) || mm g1 (bN1 -> G1)
    {
        int nb1 = (N2 + 63) / 64, nb2 = (N1 + 63) / 64;
        k_mmd2<<<nb1 + nb2, 256, 0, stream>>>(bN2, WtE1, be1, h2, rowptr + B_I1, N2, nb1,
                                              bN1, WtG1, bg1, G1, N1);
    }
    // L10: g2 gcn-gather (h2 -> bN2) || mm g0 (agg -> G0)
    {
        int nb1 = (N2 * 32 + 255) / 256;
        int nb2 = (N0 + 63) / 64;
        k_g32_mmd<<<nb1 + nb2, 256, 0, stream>>>(h2, rowptr + B_G2, od + OB_G2, bN2, N2, nb1,
                                                 agg, WtG0, bg0, G0, N0, col);
    }
    // L11: double mm — G2 = bN2@Wg2+bg2 (global+LDS), pN2 = G2@Wd0+bd0
    k_mmdd<<<(N2 + 63) / 64, 256, 0, stream>>>(bN2, WtG2, bg2, G2, WtD0, bd0, pN2, N2);
    // L12: dec0 mean-gather (pN2 -> D1)
    k_g32<0><<<(N1 * 32 + 255) / 256, 256, 0, stream>>>(pN2, rowptr + B_D0, col, nullptr, D1, N1);
    // L13: mm dec1 (D1 -> bN1)
    k_mmd<false><<<(N1 + 63) / 64, 256, 0, stream>>>(D1, WtD1, bd1, bN1, nullptr, N1);
    // L14: heads fused; head0 gathers d0 from bN1 via dec1 CSR on the fly
    {
        int nb0 = (N0 + 31) / 32, nb1 = (N1 + 31) / 32, nb2 = (N2 + 31) / 32;
        k_head3<<<nb0 + nb1 + nb2, 256, 0, stream>>>(G0, bN1, rowptr + B_D1, col, Wh0, bh0, nb0,
                                                     G1, D1, Wh1, bh1, nb1,
                                                     G2, Wh2, bh2, out);
    }
}